// Round 5
// baseline (140.385 us; speedup 1.0000x reference)
//
#include <hip/hip_runtime.h>
#include <hip/hip_bf16.h>

constexpr int CH = 128;    // channels
constexpr int NPOS = 4096; // h*w
constexpr int NB = 4;      // batch
constexpr int SPLITS = 16; // split-K factor for flash attention (R5: 8->16)

typedef __bf16 bf16x8 __attribute__((ext_vector_type(8)));
typedef float f32x2 __attribute__((ext_vector_type(2)));
typedef float f32x16 __attribute__((ext_vector_type(16)));

// (1/sqrt(128)) * log2(e): fold softmax scale into Qb so MFMA emits exp2-domain
constexpr float CSC = 0.08838834764831845f * 1.4426950408889634f;

// Frag-native layout for Q/K (mfma_32x32x16 A/B operand order):
// [b][t32 = pos>>5][kf = c>>4][lane][j]; lane = (pos&31) + 32*((c>>3)&1),
// j = c&7. One (t32,kf) chunk = contiguous 1 KB; one t32 tile = 8 KB.

// ---------------------------------------------------------------------------
// Fuse kernel: Wqk = Wk @ Wq, bqk = Wk@bq + bk; bf16 copies of Wq, Wqk.
// ---------------------------------------------------------------------------
__global__ __launch_bounds__(128) void fuse_w_kernel(
    const float* __restrict__ Wq, const float* __restrict__ bq,
    const float* __restrict__ Wk, const float* __restrict__ bk,
    __bf16* __restrict__ Wqb, __bf16* __restrict__ Wqkb,
    float* __restrict__ bqk) {
  __shared__ float red[CH];
  const int o = blockIdx.x;
  const int i = threadIdx.x;
  float acc = 0.f;
#pragma unroll 8
  for (int m = 0; m < CH; m++) acc += Wk[o * CH + m] * Wq[m * CH + i];
  Wqkb[o * CH + i] = (__bf16)acc;
  Wqb[o * CH + i] = (__bf16)Wq[o * CH + i];
  red[i] = Wk[o * CH + i] * bq[i];
  __syncthreads();
  if (i == 0) {
    float s = 0.f;
    for (int m = 0; m < CH; m++) s += red[m];
    bqk[o] = s + bk[o];
  }
}

// ---------------------------------------------------------------------------
// Projection via mfma_32x32x16_bf16. Z-FUSED: grid 512 x 512 threads; block
// = (b, u); waves 0-3 compute Q (n = wave), waves 4-7 compute K. The A
// fragment depends only on lane, so the 32x128 feature0 tile is staged ONCE
// into LDS in frag-native bf16 layout.
// ---------------------------------------------------------------------------
__global__ __launch_bounds__(512) void proj_kernel(
    const float* __restrict__ feature0, const __bf16* __restrict__ Wqb,
    const float* __restrict__ bq, const __bf16* __restrict__ Wqkb,
    const float* __restrict__ bqk, __bf16* __restrict__ Qf,
    __bf16* __restrict__ Kf) {
  __shared__ __bf16 Alds[8 * 512];  // 8 chunks x (64 lanes x 8) = 8 KB

  const int bid = blockIdx.x;  // 512 blocks
  const int b = (bid >> 1) & 3;
  const int u = (bid >> 3) * 2 + (bid & 1);  // 0..127 (pos tile)
  const int tid = threadIdx.x;
  const int lane = tid & 63;
  const int half = lane >> 5, l31 = lane & 31;
  const int wv = tid >> 6;         // 8 waves
  const int z = wv >> 2, n = wv & 3;

  // ---- cooperative stage: feature0[c][u*32+p] -> frag-native bf16 LDS ----
  {
    const int p = tid & 31;         // position within tile
    const int c0 = tid >> 5;        // 0..15
    const float* src = feature0 + (size_t)(b * CH) * NPOS + u * 32 + p;
#pragma unroll
    for (int r = 0; r < 8; r++) {
      const int c = r * 16 + c0;    // channel
      const float v = src[(size_t)c * NPOS];
      const int ks = c >> 4, hf = (c >> 3) & 1, j = c & 7;
      Alds[ks * 512 + (p + 32 * hf) * 8 + j] = (__bf16)v;
    }
  }
  __syncthreads();

  bf16x8 A[8];
#pragma unroll
  for (int ks = 0; ks < 8; ks++)
    A[ks] = *(const bf16x8*)(&Alds[ks * 512 + lane * 8]);

  const __bf16* W = z ? Wqkb : Wqb;
  const float* bias = z ? bqk : bq;
  __bf16* Out = z ? Kf : Qf;
  const float scale = z ? 1.0f : CSC;

  const int co = n * 32 + l31;
  const bf16x8* Bp = (const bf16x8*)(W + co * CH + half * 8);
  f32x16 c = {0.f, 0.f, 0.f, 0.f, 0.f, 0.f, 0.f, 0.f,
              0.f, 0.f, 0.f, 0.f, 0.f, 0.f, 0.f, 0.f};
#pragma unroll
  for (int ks = 0; ks < 8; ks++)
    c = __builtin_amdgcn_mfma_f32_32x32x16_bf16(A[ks], Bp[ks * 2], c, 0, 0, 0);
  const float bv = bias[co];
  const int kf = n * 2 + (l31 >> 4);
  const int lanebit = (l31 >> 3) & 1;
  const int j = l31 & 7;
#pragma unroll
  for (int r = 0; r < 16; r++) {
    int roff = (r & 3) + 8 * (r >> 2) + 4 * half;  // pos offset in tile
    Out[((((size_t)(b * (NPOS / 32) + u)) * 8 + kf) * 64 +
         (roff + 32 * lanebit)) * 8 + j] = (__bf16)((c[r] + bv) * scale);
  }
}

// ---------------------------------------------------------------------------
// Flash attention R5: NO K-LDS STAGING, NO MAIN-LOOP BARRIERS.
// R4 profile: attn = 44 us with MfmaUtil 14% / VALUBusy 21% / HBM 2% /
// occupancy 13% -> ~90% stall from the per-tile vmcnt+s_barrier DMA
// choreography at 2 waves/SIMD. Kf is 1 MB/batch (L2-resident with the
// b->XCD affinity), so stage NOTHING (m169 pattern): each wave loads its
// B-fragments straight from global (global_load_dwordx4, L2 hit), 8
// independent loads/tile, and the compiler software-pipelines across tiles
// freely. SPLITS 8->16 doubles block concurrency (1024 blocks); NT=8.
// Each wave still owns TWO 32-row q-tiles (each fragment feeds 2 MFMAs).
// ---------------------------------------------------------------------------
__global__ __launch_bounds__(256, 2) void attn_kernel(
    const __bf16* __restrict__ Qf, const __bf16* __restrict__ Kf,
    const float* __restrict__ flow, float* __restrict__ part) {
  __shared__ float flds[2 * (NPOS / SPLITS)];  // split's flow values (2 KB)
  __shared__ float red[256 * 3];

  const int bid = blockIdx.x;  // 1024 blocks
  const int b = (bid >> 1) & 3;
  const int u = (bid >> 3) * 2 + (bid & 1);  // 0..255 per batch
  const int split = u >> 4;                  // 16 splits
  const int qg = u & 15;                     // 16 q-groups of 256 rows

  const int tid = threadIdx.x;
  const int wave = tid >> 6, lane = tid & 63;  // wave 0..3
  const int half = lane >> 5, l31 = lane & 31;
  const int kbase = split * (NPOS / SPLITS);  // 256 keys per split
  constexpr int NT = NPOS / SPLITS / 32;      // 8 tiles of 32 keys

  // stage flow for this split into LDS (one-time)
  {
    const float* fl0 = flow + (size_t)(b * 2 + 0) * NPOS + kbase;
    const float* fl1 = flow + (size_t)(b * 2 + 1) * NPOS + kbase;
    flds[tid] = fl0[tid];
    flds[256 + tid] = fl1[tid];
  }
  __syncthreads();

  // Q fragments: wave's two q-tiles qt0, qt0+1 (CSC pre-folded)
  const int qt0 = qg * 8 + wave * 2;  // 0..126, even
  bf16x8 qf0[8], qf1[8];
  {
    const bf16x8* Qp =
        (const bf16x8*)Qf + ((size_t)(b * (NPOS / 32) + qt0) * 8) * 64 + lane;
#pragma unroll
    for (int kf = 0; kf < 8; kf++) {
      qf0[kf] = Qp[kf * 64];
      qf1[kf] = Qp[512 + kf * 64];  // next tile = +512 bf16x8
    }
  }

  // K tile base for this (b, split): 8 contiguous 8 KB frag-native tiles
  const bf16x8* Ktb =
      (const bf16x8*)(Kf + ((size_t)(b * (NPOS / 32) + (kbase >> 5))) * 4096) +
      lane;

  float ls0[16], ls1[16];
  f32x2 av0[16], av1[16];
#pragma unroll
  for (int r = 0; r < 16; r++) {
    ls0[r] = 0.f;
    ls1[r] = 0.f;
    av0[r] = f32x2{0.f, 0.f};
    av1[r] = f32x2{0.f, 0.f};
  }

  for (int t = 0; t < NT; t++) {
    const bf16x8* kb = Ktb + (size_t)t * 512;  // tile t, this lane's 16 B
    f32x16 c0 = {0.f, 0.f, 0.f, 0.f, 0.f, 0.f, 0.f, 0.f,
                 0.f, 0.f, 0.f, 0.f, 0.f, 0.f, 0.f, 0.f};
    f32x16 c1 = {0.f, 0.f, 0.f, 0.f, 0.f, 0.f, 0.f, 0.f,
                 0.f, 0.f, 0.f, 0.f, 0.f, 0.f, 0.f, 0.f};
#pragma unroll
    for (int kf = 0; kf < 8; kf++) {
      bf16x8 bfrag = kb[kf * 64];  // global_load_dwordx4, L2-resident
      c0 = __builtin_amdgcn_mfma_f32_32x32x16_bf16(qf0[kf], bfrag, c0, 0, 0, 0);
      c1 = __builtin_amdgcn_mfma_f32_32x32x16_bf16(qf1[kf], bfrag, c1, 0, 0, 0);
    }
    const f32x2 v01 = {flds[t * 32 + l31], flds[256 + t * 32 + l31]};
#pragma unroll
    for (int r = 0; r < 16; r++) {
      float p0 = __builtin_amdgcn_exp2f(c0[r]);
      ls0[r] += p0;
      av0[r] += f32x2{p0, p0} * v01;
      float p1 = __builtin_amdgcn_exp2f(c1[r]);
      ls1[r] += p1;
      av1[r] += f32x2{p1, p1} * v01;
    }
  }

  // reduce across the 32 key-lanes (butterfly stays within each 32-lane half)
#pragma unroll
  for (int r = 0; r < 16; r++) {
#pragma unroll
    for (int st = 1; st < 32; st <<= 1) {
      ls0[r] += __shfl_xor(ls0[r], st, 64);
      av0[r][0] += __shfl_xor(av0[r][0], st, 64);
      av0[r][1] += __shfl_xor(av0[r][1], st, 64);
      ls1[r] += __shfl_xor(ls1[r], st, 64);
      av1[r][0] += __shfl_xor(av1[r][0], st, 64);
      av1[r][1] += __shfl_xor(av1[r][1], st, 64);
    }
  }
  if (l31 == 0) {
#pragma unroll
    for (int r = 0; r < 16; r++) {
      int roff = (r & 3) + 8 * (r >> 2) + 4 * half;
      int ql0 = (wave * 2 + 0) * 32 + roff;
      int ql1 = (wave * 2 + 1) * 32 + roff;
      red[ql0 * 3 + 0] = ls0[r];
      red[ql0 * 3 + 1] = av0[r][0];
      red[ql0 * 3 + 2] = av0[r][1];
      red[ql1 * 3 + 0] = ls1[r];
      red[ql1 * 3 + 1] = av1[r][0];
      red[ql1 * 3 + 2] = av1[r][1];
    }
  }
  __syncthreads();
  for (int idx = tid; idx < 256 * 3; idx += 256) {
    int plane = idx >> 8, ql = idx & 255;
    part[((size_t)(plane * SPLITS + split) * NB + b) * NPOS + qg * 256 + ql] =
        red[ql * 3 + plane];
  }
}

// ---------------------------------------------------------------------------
// Combine: sum split partials per plane, normalize, write out[b][2][n].
// ---------------------------------------------------------------------------
__global__ __launch_bounds__(256) void combine_kernel(
    const float* __restrict__ part, float* __restrict__ out) {
  int t = blockIdx.x * 256 + threadIdx.x;  // 0 .. NB*NPOS-1
  int b = t >> 12, q = t & (NPOS - 1);
  float l = 0.f, x = 0.f, y = 0.f;
#pragma unroll
  for (int s = 0; s < SPLITS; s++) {
    l += part[((size_t)(0 * SPLITS + s) * NB + b) * NPOS + q];
    x += part[((size_t)(1 * SPLITS + s) * NB + b) * NPOS + q];
    y += part[((size_t)(2 * SPLITS + s) * NB + b) * NPOS + q];
  }
  float inv = 1.0f / l;
  out[(size_t)(b * 2 + 0) * NPOS + q] = x * inv;
  out[(size_t)(b * 2 + 1) * NPOS + q] = y * inv;
}

extern "C" void kernel_launch(void* const* d_in, const int* in_sizes, int n_in,
                              void* d_out, int out_size, void* d_ws,
                              size_t ws_size, hipStream_t stream) {
  const float* feature0 = (const float*)d_in[0];
  const float* flow = (const float*)d_in[1];
  const float* Wq = (const float*)d_in[2];
  const float* bq = (const float*)d_in[3];
  const float* Wk = (const float*)d_in[4];
  const float* bk = (const float*)d_in[5];
  float* out = (float*)d_out;

  char* ws = (char*)d_ws;
  __bf16* Qf = (__bf16*)ws;                                 // 4 MB
  __bf16* Kf = (__bf16*)(ws + (4 << 20));                   // 4 MB
  __bf16* Wqb = (__bf16*)(ws + (8 << 20));                  // 32 KB
  __bf16* Wqkb = (__bf16*)(ws + (8 << 20) + (32 << 10));    // 32 KB
  float* bqk = (float*)(ws + (8 << 20) + (64 << 10));       // 512 B
  float* part = (float*)(ws + (8 << 20) + (128 << 10));     // 3 MB

  fuse_w_kernel<<<dim3(CH), 128, 0, stream>>>(Wq, bq, Wk, bk, Wqb, Wqkb, bqk);
  proj_kernel<<<dim3(512), 512, 0, stream>>>(feature0, Wqb, bq, Wqkb, bqk, Qf,
                                             Kf);
  attn_kernel<<<dim3(NB * SPLITS * 16), 256, 0, stream>>>(Qf, Kf, flow, part);
  combine_kernel<<<dim3(NB * NPOS / 256), 256, 0, stream>>>(part, out);
}

// Round 6
// 105.950 us; speedup vs baseline: 1.3250x; 1.3250x over previous
//
#include <hip/hip_runtime.h>
#include <hip/hip_bf16.h>

constexpr int CH = 128;    // channels
constexpr int NPOS = 4096; // h*w
constexpr int NB = 4;      // batch
constexpr int SPLITS = 8;  // split-K factor for flash attention

typedef __bf16 bf16x8 __attribute__((ext_vector_type(8)));
typedef float f32x2 __attribute__((ext_vector_type(2)));
typedef float f32x4 __attribute__((ext_vector_type(4)));
typedef float f32x16 __attribute__((ext_vector_type(16)));

// (1/sqrt(128)) * log2(e): fold softmax scale into Qb so MFMA emits exp2-domain
constexpr float CSC = 0.08838834764831845f * 1.4426950408889634f;

// Frag-native layout for Q/K (mfma_32x32x16 A/B operand order):
// [b][t32 = pos>>5][kf = c>>4][lane][j]; lane = (pos&31) + 32*((c>>3)&1),
// j = c&7. One (t32,kf) chunk = contiguous 1 KB; one t32 tile = 8 KB.

// Async global->LDS DMA, 16B per lane, LDS dst = wave-uniform base + lane*16.
__device__ __forceinline__ void async_copy16(const void* g, void* l) {
  auto gp = (const __attribute__((address_space(1))) unsigned int*)((uintptr_t)g);
  auto lp = (__attribute__((address_space(3))) unsigned int*)((uintptr_t)l);
  __builtin_amdgcn_global_load_lds(gp, lp, 16, 0, 0);
}

// Barrier requesting only the N oldest DMAs may remain in flight.
#define PIPE_BARRIER(N)                                              \
  asm volatile("s_waitcnt vmcnt(" #N ") lgkmcnt(0)\n\ts_barrier" ::: "memory")

// ---------------------------------------------------------------------------
// Fuse kernel: Wqk = Wk @ Wq, bqk = Wk@bq + bk; bf16 copies of Wq, Wqk.
// ---------------------------------------------------------------------------
__global__ __launch_bounds__(128) void fuse_w_kernel(
    const float* __restrict__ Wq, const float* __restrict__ bq,
    const float* __restrict__ Wk, const float* __restrict__ bk,
    __bf16* __restrict__ Wqb, __bf16* __restrict__ Wqkb,
    float* __restrict__ bqk) {
  __shared__ float red[CH];
  const int o = blockIdx.x;
  const int i = threadIdx.x;
  float acc = 0.f;
#pragma unroll 8
  for (int m = 0; m < CH; m++) acc += Wk[o * CH + m] * Wq[m * CH + i];
  Wqkb[o * CH + i] = (__bf16)acc;
  Wqb[o * CH + i] = (__bf16)Wq[o * CH + i];
  red[i] = Wk[o * CH + i] * bq[i];
  __syncthreads();
  if (i == 0) {
    float s = 0.f;
    for (int m = 0; m < CH; m++) s += red[m];
    bqk[o] = s + bk[o];
  }
}

// ---------------------------------------------------------------------------
// Projection via mfma_32x32x16_bf16. Z-FUSED: grid 512 x 512 threads; block
// = (b, u); waves 0-3 compute Q (n = wave), waves 4-7 compute K. The A
// fragment depends only on lane, so the 32x128 feature0 tile is staged ONCE
// into LDS in frag-native bf16 layout.
// ---------------------------------------------------------------------------
__global__ __launch_bounds__(512) void proj_kernel(
    const float* __restrict__ feature0, const __bf16* __restrict__ Wqb,
    const float* __restrict__ bq, const __bf16* __restrict__ Wqkb,
    const float* __restrict__ bqk, __bf16* __restrict__ Qf,
    __bf16* __restrict__ Kf) {
  __shared__ __bf16 Alds[8 * 512];  // 8 chunks x (64 lanes x 8) = 8 KB

  const int bid = blockIdx.x;  // 512 blocks
  const int b = (bid >> 1) & 3;
  const int u = (bid >> 3) * 2 + (bid & 1);  // 0..127 (pos tile)
  const int tid = threadIdx.x;
  const int lane = tid & 63;
  const int half = lane >> 5, l31 = lane & 31;
  const int wv = tid >> 6;         // 8 waves
  const int z = wv >> 2, n = wv & 3;

  // ---- cooperative stage: feature0[c][u*32+p] -> frag-native bf16 LDS ----
  {
    const int p = tid & 31;         // position within tile
    const int c0 = tid >> 5;        // 0..15
    const float* src = feature0 + (size_t)(b * CH) * NPOS + u * 32 + p;
#pragma unroll
    for (int r = 0; r < 8; r++) {
      const int c = r * 16 + c0;    // channel
      const float v = src[(size_t)c * NPOS];
      const int ks = c >> 4, hf = (c >> 3) & 1, j = c & 7;
      Alds[ks * 512 + (p + 32 * hf) * 8 + j] = (__bf16)v;
    }
  }
  __syncthreads();

  bf16x8 A[8];
#pragma unroll
  for (int ks = 0; ks < 8; ks++)
    A[ks] = *(const bf16x8*)(&Alds[ks * 512 + lane * 8]);

  const __bf16* W = z ? Wqkb : Wqb;
  const float* bias = z ? bqk : bq;
  __bf16* Out = z ? Kf : Qf;
  const float scale = z ? 1.0f : CSC;

  const int co = n * 32 + l31;
  const bf16x8* Bp = (const bf16x8*)(W + co * CH + half * 8);
  f32x16 c = {0.f, 0.f, 0.f, 0.f, 0.f, 0.f, 0.f, 0.f,
              0.f, 0.f, 0.f, 0.f, 0.f, 0.f, 0.f, 0.f};
#pragma unroll
  for (int ks = 0; ks < 8; ks++)
    c = __builtin_amdgcn_mfma_f32_32x32x16_bf16(A[ks], Bp[ks * 2], c, 0, 0, 0);
  const float bv = bias[co];
  const int kf = n * 2 + (l31 >> 4);
  const int lanebit = (l31 >> 3) & 1;
  const int j = l31 & 7;
#pragma unroll
  for (int r = 0; r < 16; r++) {
    int roff = (r & 3) + 8 * (r >> 2) + 4 * half;  // pos offset in tile
    Out[((((size_t)(b * (NPOS / 32) + u)) * 8 + kf) * 64 +
         (roff + 32 * lanebit)) * 8 + j] = (__bf16)((c[r] + bv) * scale);
  }
}

// ---------------------------------------------------------------------------
// Flash attention R6 = R3's verified main loop (256 threads, 4 waves, each
// wave owns TWO 32-row q-tiles, 3-deep DMA circular buffer) + NEW EPILOGUE:
// the 480-shfl/wave butterfly (ds_bpermute on the DS pipe, ~3840 ops/CU ~
// 10-19 us/CU of serialization -- the unexplained idle in R4's profile) is
// replaced by an LDS-transpose reduction: write partials to a padded
// [256][36] f32 scratch (rows 16B-aligned, bank-spread; conflict-free
// writes), then each thread sums one q-row with 8x ds_read_b128.
// DS insts/wave: ~530 -> ~120; removes 480 dependent VALU adds. Scratch
// aliases the Klds arena (main loop done). Exact-f32 reorder only.
// ---------------------------------------------------------------------------
__global__ __launch_bounds__(256, 2) void attn_kernel(
    const __bf16* __restrict__ Qf, const __bf16* __restrict__ Kf,
    const float* __restrict__ flow, float* __restrict__ part) {
  __shared__ char arena[256 * 36 * 4];  // 36 KB: Klds+flds (main) / scratch
  __bf16(*Klds)[8 * 512] = (__bf16(*)[8 * 512])arena;  // 3 x 8 KB
  float* flds = (float*)(arena + 24576);               // 4 KB
  float* scratch = (float*)arena;                      // epilogue [256][36]

  const int bid = blockIdx.x;  // 512 blocks
  const int b = (bid >> 1) & 3;
  const int u = (bid >> 3) * 2 + (bid & 1);  // 0..127 per batch
  const int split = u >> 4;                  // 8 splits
  const int qg = u & 15;                     // 16 q-groups of 256 rows

  const int tid = threadIdx.x;
  const int wave = tid >> 6, lane = tid & 63;  // wave 0..3
  const int half = lane >> 5, l31 = lane & 31;
  const int kbase = split * (NPOS / SPLITS);  // 512 keys per split
  constexpr int NT = NPOS / SPLITS / 32;      // 16 tiles of 32 keys

  // stage flow for this split into LDS (one-time; fenced by first barrier)
  {
    const float* fl0 = flow + (size_t)(b * 2 + 0) * NPOS + kbase;
    const float* fl1 = flow + (size_t)(b * 2 + 1) * NPOS + kbase;
    flds[tid] = fl0[tid];
    flds[256 + tid] = fl0[256 + tid];
    flds[512 + tid] = fl1[tid];
    flds[768 + tid] = fl1[256 + tid];
  }

  // Q fragments: wave's two q-tiles qt0, qt0+1 (CSC pre-folded)
  const int qt0 = qg * 8 + wave * 2;  // 0..126, even
  bf16x8 qf0[8], qf1[8];
  {
    const bf16x8* Qp =
        (const bf16x8*)Qf + ((size_t)(b * (NPOS / 32) + qt0) * 8) * 64 + lane;
#pragma unroll
    for (int kf = 0; kf < 8; kf++) {
      qf0[kf] = Qp[kf * 64];
      qf1[kf] = Qp[512 + kf * 64];  // next tile = +512 bf16x8
    }
  }

  // K tile base for this (b, split): 16 contiguous 8 KB frag-native tiles
  const __bf16* Ktb = Kf + ((size_t)(b * (NPOS / 32) + (kbase >> 5))) * 4096;

  // wave w stages chunks {2w, 2w+1} (2 KB) of each tile: 2 DMA insts/wave
  auto issue = [&](int t, int buf) {
    const __bf16* g = Ktb + (size_t)t * 4096;
    const int c0 = wave * 1024;
    async_copy16(g + c0 + lane * 8, &Klds[buf][c0 + lane * 8]);
    async_copy16(g + c0 + 512 + lane * 8, &Klds[buf][c0 + 512 + lane * 8]);
  };
  issue(0, 0);
  issue(1, 1);

  float ls0[16], ls1[16];
  f32x2 av0[16], av1[16];
#pragma unroll
  for (int r = 0; r < 16; r++) {
    ls0[r] = 0.f;
    ls1[r] = 0.f;
    av0[r] = f32x2{0.f, 0.f};
    av1[r] = f32x2{0.f, 0.f};
  }

  int bcur = 0, bnext = 2;  // buffer of tile t; buffer for tile t+2
  for (int t = 0; t < NT; t++) {
    if (t < NT - 1) {
      PIPE_BARRIER(2);  // tile t's 2 DMAs retired; tile t+1's stay in flight
    } else {
      PIPE_BARRIER(0);  // final tile: full drain
    }
    if (t + 2 < NT) issue(t + 2, bnext);

    const __bf16* kb = &Klds[bcur][0];
    f32x16 c0 = {0.f, 0.f, 0.f, 0.f, 0.f, 0.f, 0.f, 0.f,
                 0.f, 0.f, 0.f, 0.f, 0.f, 0.f, 0.f, 0.f};
    f32x16 c1 = {0.f, 0.f, 0.f, 0.f, 0.f, 0.f, 0.f, 0.f,
                 0.f, 0.f, 0.f, 0.f, 0.f, 0.f, 0.f, 0.f};
#pragma unroll
    for (int kf = 0; kf < 8; kf++) {
      bf16x8 bfrag = *(const bf16x8*)(kb + kf * 512 + lane * 8);
      c0 = __builtin_amdgcn_mfma_f32_32x32x16_bf16(qf0[kf], bfrag, c0, 0, 0, 0);
      c1 = __builtin_amdgcn_mfma_f32_32x32x16_bf16(qf1[kf], bfrag, c1, 0, 0, 0);
    }
    const f32x2 v01 = {flds[t * 32 + l31], flds[512 + t * 32 + l31]};
#pragma unroll
    for (int r = 0; r < 16; r++) {
      float p0 = __builtin_amdgcn_exp2f(c0[r]);
      ls0[r] += p0;
      av0[r] += f32x2{p0, p0} * v01;
      float p1 = __builtin_amdgcn_exp2f(c1[r]);
      ls1[r] += p1;
      av1[r] += f32x2{p1, p1} * v01;
    }
    bcur = (bcur == 2) ? 0 : bcur + 1;
    bnext = (bnext == 2) ? 0 : bnext + 1;
  }

  // ---- LDS-transpose reduction (replaces the 5-stage shfl butterfly) ----
  // scratch[qrow 0..255][l31 0..31], row stride 36 f32 = 144 B (16B-aligned,
  // banks spread by 4*row). Writes: lanes of a half share a row, cols=l31 ->
  // conflict-free. Reads: 8x ds_read_b128 per thread (1 KB/inst baseline).
#pragma unroll
  for (int plane = 0; plane < 3; plane++) {
    __syncthreads();  // plane 0: main loop done with Klds/flds; else: drain
#pragma unroll
    for (int r = 0; r < 16; r++) {
      const int roff = (r & 3) + 8 * (r >> 2) + 4 * half;
      const float v0 =
          (plane == 0) ? ls0[r] : ((plane == 1) ? av0[r][0] : av0[r][1]);
      const float v1 =
          (plane == 0) ? ls1[r] : ((plane == 1) ? av1[r][0] : av1[r][1]);
      scratch[(wave * 64 + roff) * 36 + l31] = v0;
      scratch[(wave * 64 + 32 + roff) * 36 + l31] = v1;
    }
    __syncthreads();
    f32x4 a4 = {0.f, 0.f, 0.f, 0.f};
    const f32x4* rowp = (const f32x4*)(scratch + tid * 36);
#pragma unroll
    for (int j = 0; j < 8; j++) a4 += rowp[j];
    part[((size_t)(plane * SPLITS + split) * NB + b) * NPOS + qg * 256 + tid] =
        a4[0] + a4[1] + a4[2] + a4[3];
  }
}

// ---------------------------------------------------------------------------
// Combine: sum split partials per plane, normalize, write out[b][2][n].
// ---------------------------------------------------------------------------
__global__ __launch_bounds__(256) void combine_kernel(
    const float* __restrict__ part, float* __restrict__ out) {
  int t = blockIdx.x * 256 + threadIdx.x;  // 0 .. NB*NPOS-1
  int b = t >> 12, q = t & (NPOS - 1);
  float l = 0.f, x = 0.f, y = 0.f;
#pragma unroll
  for (int s = 0; s < SPLITS; s++) {
    l += part[((size_t)(0 * SPLITS + s) * NB + b) * NPOS + q];
    x += part[((size_t)(1 * SPLITS + s) * NB + b) * NPOS + q];
    y += part[((size_t)(2 * SPLITS + s) * NB + b) * NPOS + q];
  }
  float inv = 1.0f / l;
  out[(size_t)(b * 2 + 0) * NPOS + q] = x * inv;
  out[(size_t)(b * 2 + 1) * NPOS + q] = y * inv;
}

extern "C" void kernel_launch(void* const* d_in, const int* in_sizes, int n_in,
                              void* d_out, int out_size, void* d_ws,
                              size_t ws_size, hipStream_t stream) {
  const float* feature0 = (const float*)d_in[0];
  const float* flow = (const float*)d_in[1];
  const float* Wq = (const float*)d_in[2];
  const float* bq = (const float*)d_in[3];
  const float* Wk = (const float*)d_in[4];
  const float* bk = (const float*)d_in[5];
  float* out = (float*)d_out;

  char* ws = (char*)d_ws;
  __bf16* Qf = (__bf16*)ws;                                 // 4 MB
  __bf16* Kf = (__bf16*)(ws + (4 << 20));                   // 4 MB
  __bf16* Wqb = (__bf16*)(ws + (8 << 20));                  // 32 KB
  __bf16* Wqkb = (__bf16*)(ws + (8 << 20) + (32 << 10));    // 32 KB
  float* bqk = (float*)(ws + (8 << 20) + (64 << 10));       // 512 B
  float* part = (float*)(ws + (8 << 20) + (128 << 10));     // 1.5 MB

  fuse_w_kernel<<<dim3(CH), 128, 0, stream>>>(Wq, bq, Wk, bk, Wqb, Wqkb, bqk);
  proj_kernel<<<dim3(512), 512, 0, stream>>>(feature0, Wqb, bq, Wqkb, bqk, Qf,
                                             Kf);
  attn_kernel<<<dim3(512), 256, 0, stream>>>(Qf, Kf, flow, part);
  combine_kernel<<<dim3(NB * NPOS / 256), 256, 0, stream>>>(part, out);
}